// Round 4
// baseline (208.564 us; speedup 1.0000x reference)
//
#include <hip/hip_runtime.h>
#include <hip/hip_cooperative_groups.h>

namespace cg = cooperative_groups;

// RelativePositionAttention collapses algebraically:
//   softmax over w of (Q[t] - K[w]) is independent of Q (shift invariance),
//   and einsum('btdh,btwdh->btdh', Vh, A) = Vh * sum_w A = Vh.
// So: result = values @ M^T, with
//   M[i][j] = sum_{h,d} Wp[i*EH + d*H + h] * Wv[(h*E + d)*E + j]   (256x256)
// LayerNorm / Wq / Wk / position_embeddings are dead code.
//
// R4: dur_us is dominated by harness fixed costs (268MB d_ws poison fill
// ~41us + restore copies + per-dispatch graph gaps). Controllable part is
// dispatch count: fuse memset+build+apply into ONE cooperative kernel with
// grid.sync() between phases. 256 blocks x 1024 thr = 1 block/CU, trivially
// co-resident; 38 KB LDS.

constexpr int E  = 256;
constexpr int H  = 4;
constexpr int EH = E * H;   // 1024

__global__ __launch_bounds__(1024) void fused_kernel(
    const float* __restrict__ values, const float* __restrict__ Wv,
    const float* __restrict__ Wp, float* __restrict__ MT,
    float* __restrict__ out)
{
    cg::grid_group grid = cg::this_grid();
    const int tid = threadIdx.x;
    const int b   = blockIdx.x;          // 0..255

    __shared__ float sWp [4][256];       //  4 KB  (phase 1 Wp stage)
    __shared__ float sAcc[4][4][256];    // 16 KB  (phase 1 k-reduce)
    __shared__ float sv  [2][256];       //  2 KB  (phase 2 values stage)
    __shared__ float sAc2[8][2][256];    // 16 KB  (phase 2 j-reduce)

    // ---- phase 0: zero MT (65536 floats; blocks 0..63 cover it)
    {
        const int idx = b * 1024 + tid;
        if (idx < E * E) MT[idx] = 0.f;
    }
    grid.sync();

    // ---- phase 1: build MT. block b -> rows i0=(b>>2)*4, d-quarter (b&3)*64.
    // thread: jq=tid&63 -> cols j0=jq*4 (float4), w=(tid>>6)&3 -> row,
    // skc=tid>>8 -> d-sub of 16. LDS-reduce over skc, coalesced 16B atomics.
    {
        const int i0 = (b >> 2) * 4;
        const int dB = (b & 3) * 64;
        const int jq = tid & 63, j0 = jq * 4;
        const int w  = (tid >> 6) & 3;
        const int skc = tid >> 8;        // 0..3

        // Wp rows i0..i0+3, col block [(b&3)*256, +256) (col = d*4+h contiguous)
        sWp[tid >> 8][tid & 255] = Wp[(i0 + (tid >> 8)) * EH + (b & 3) * 256 + (tid & 255)];
        __syncthreads();

        float4 acc = make_float4(0.f, 0.f, 0.f, 0.f);
        #pragma unroll
        for (int h = 0; h < H; ++h) {
            const float* __restrict__ p = Wv + (h * E + dB + skc * 16) * E + j0;
            #pragma unroll
            for (int dd = 0; dd < 16; ++dd) {
                const float4 wv = *(const float4*)(p + dd * E);     // 16B coalesced
                const float  wp = sWp[w][(skc * 16 + dd) * 4 + h];  // LDS broadcast
                acc.x += wp * wv.x; acc.y += wp * wv.y;
                acc.z += wp * wv.z; acc.w += wp * wv.w;
            }
        }

        *(float4*)&sAcc[skc][w][j0] = acc;   // wave-uniform skc,w -> conflict-free
        __syncthreads();

        const int j2 = tid >> 2;             // 0..255
        const int ii = tid & 3;              // row offset
        const float v = sAcc[0][ii][j2] + sAcc[1][ii][j2]
                      + sAcc[2][ii][j2] + sAcc[3][ii][j2];
        atomicAdd(&MT[j2 * E + i0 + ii], v); // wave = 16 segments of 16B
    }
    __threadfence();
    grid.sync();   // device-scope fence: MT visible across XCDs

    // ---- phase 2: apply. block b -> rows r0=2b, 2b+1.
    // thread: eq=tid&63 -> e0=eq*4 (float4), rr=(tid>>6)&1 -> row,
    // jc=tid>>7 -> j-chunk of 32. LDS j-reduce, coalesced stores.
    {
        const int r0 = b * 2;
        const int eq = tid & 63, e0 = eq * 4;
        const int rr = (tid >> 6) & 1;
        const int jc = tid >> 7;             // 0..7

        if (tid < 2 * E) sv[tid >> 8][tid & 255] = values[r0 * E + tid];
        __syncthreads();

        float4 acc = make_float4(0.f, 0.f, 0.f, 0.f);
        #pragma unroll
        for (int jj = 0; jj < 32; ++jj) {
            const int    j = jc * 32 + jj;
            const float4 m = *(const float4*)&MT[j * E + e0];   // 16B coalesced
            const float  s = sv[rr][j];                         // LDS broadcast
            acc.x += s * m.x; acc.y += s * m.y;
            acc.z += s * m.z; acc.w += s * m.w;
        }

        *(float4*)&sAc2[jc][rr][e0] = acc;   // wave-uniform jc,rr -> conflict-free
        __syncthreads();

        if (tid < 2 * E) {
            const int r_idx = tid >> 8, e = tid & 255;
            float v = 0.f;
            #pragma unroll
            for (int c = 0; c < 8; ++c) v += sAc2[c][r_idx][e]; // conflict-free
            out[(r0 + r_idx) * E + e] = v;                      // coalesced
        }
    }
}

extern "C" void kernel_launch(void* const* d_in, const int* in_sizes, int n_in,
                              void* d_out, int out_size, void* d_ws, size_t ws_size,
                              hipStream_t stream) {
    // inputs: 0 pos_emb(unused) 1 values 2 ln_w 3 ln_b 4 Wq 5 Wk 6 Wv 7 Wp
    const float* values = (const float*)d_in[1];
    const float* Wv     = (const float*)d_in[6];
    const float* Wp     = (const float*)d_in[7];
    float*       out    = (float*)d_out;
    float*       MT     = (float*)d_ws;   // E*E floats = 256 KB scratch

    void* args[] = { (void*)&values, (void*)&Wv, (void*)&Wp, (void*)&MT, (void*)&out };
    hipLaunchCooperativeKernel((const void*)fused_kernel,
                               dim3(256), dim3(1024), args, 0, stream);
}

// Round 5
// 104.172 us; speedup vs baseline: 2.0021x; 2.0021x over previous
//
#include <hip/hip_runtime.h>

// RelativePositionAttention collapses algebraically:
//   softmax over w of (Q[t] - K[w]) is independent of Q (shift invariance),
//   and einsum('btdh,btwdh->btdh', Vh, A) = Vh * sum_w A = Vh.
// So: result = values @ M^T, with
//   M[i][j] = sum_{h,d} Wp[i*EH + d*H + h] * Wv[(h*E + d)*E + j]   (256x256)
// LayerNorm / Wq / Wk / position_embeddings are dead code.
//
// R5: R4's cooperative fusion backfired (grid.sync ~60us each on 8 XCDs;
// kernel alone 127us). Back to separate dispatches, but drop the memset
// dispatch + atomics: build does the full k=1024 contraction inside one
// block (4 wave-groups x 64 d's, LDS reduce), plain coalesced stores.
// 2 dispatches total. Harness poison fill (~41us, 268MB d_ws) is the floor.

constexpr int E  = 256;
constexpr int H  = 4;
constexpr int EH = E * H;   // 1024
constexpr int BT = 512;     // B*T

// grid 64 x 1024 thr. Block bx -> M rows i0=bx*4, full k=1024.
// thread: j0=(tid&63)*4 (float4 cols), w=(tid>>6)&3 (row), skc=tid>>8
// (d-range [skc*64, +64)). LDS-reduce over skc, coalesced plain store.
__global__ __launch_bounds__(1024) void build_m_kernel(
    const float* __restrict__ Wv, const float* __restrict__ Wp,
    float* __restrict__ MT)
{
    const int tid = threadIdx.x;
    const int j0  = (tid & 63) * 4;
    const int w   = (tid >> 6) & 3;
    const int skc = tid >> 8;            // 0..3
    const int i0  = blockIdx.x * 4;

    // Stage Wp rows i0..i0+3 (contiguous 16 KB) as one float4 copy.
    __shared__ float sWp[4][EH];         // 16 KB
    ((float4*)sWp)[tid] = ((const float4*)(Wp + i0 * EH))[tid];
    __syncthreads();

    float4 acc = make_float4(0.f, 0.f, 0.f, 0.f);
    #pragma unroll
    for (int h = 0; h < H; ++h) {
        const float* __restrict__ p = Wv + (h * E + skc * 64) * E + j0;
        #pragma unroll 16
        for (int dd = 0; dd < 64; ++dd) {
            const float4 wv = *(const float4*)(p + dd * E);        // 16B coalesced
            const float  wp = sWp[w][(skc * 64 + dd) * 4 + h];     // wave-uniform -> broadcast
            acc.x += wp * wv.x; acc.y += wp * wv.y;
            acc.z += wp * wv.z; acc.w += wp * wv.w;
        }
    }

    // reduce over skc in LDS (pad 257 to break 4-way bank conflict on read)
    __shared__ float sAcc[4][4][E + 1];  // ~16.1 KB
    sAcc[skc][w][j0 + 0] = acc.x;
    sAcc[skc][w][j0 + 1] = acc.y;
    sAcc[skc][w][j0 + 2] = acc.z;
    sAcc[skc][w][j0 + 3] = acc.w;
    __syncthreads();

    const int j2 = tid >> 2;             // 0..255
    const int ii = tid & 3;              // row offset
    const float v = sAcc[0][ii][j2] + sAcc[1][ii][j2]
                  + sAcc[2][ii][j2] + sAcc[3][ii][j2];
    MT[j2 * E + i0 + ii] = v;            // wave = 16 segments of 16B, no atomic
}

// out[r,e] = sum_j values[r,j] * MT[j*E + e]
// grid 256 x 1024 thr (1 block/CU). thread: e0=(tid&63)*4 (float4),
// rr=(tid>>6)&1 (row), jc=tid>>7 (j-chunk of 32). LDS j-reduce, coalesced.
__global__ __launch_bounds__(1024) void apply_kernel(
    const float* __restrict__ values, const float* __restrict__ MT,
    float* __restrict__ out)
{
    const int tid = threadIdx.x;
    const int e0  = (tid & 63) * 4;
    const int rr  = (tid >> 6) & 1;
    const int jc  = tid >> 7;            // 0..7
    const int r0  = blockIdx.x * 2;

    __shared__ float sv[2][E];
    if (tid < 2 * E) sv[tid >> 8][tid & 255] = values[r0 * E + tid];
    __syncthreads();

    float4 acc = make_float4(0.f, 0.f, 0.f, 0.f);
    #pragma unroll
    for (int jj = 0; jj < 32; ++jj) {
        const int    j = jc * 32 + jj;
        const float4 m = *(const float4*)&MT[j * E + e0];          // 16B coalesced
        const float  s = sv[rr][j];                                // LDS broadcast
        acc.x += s * m.x; acc.y += s * m.y; acc.z += s * m.z; acc.w += s * m.w;
    }

    __shared__ float sAc2[8][2][E];      // 16 KB; reduce reads are stride-1
    *(float4*)&sAc2[jc][rr][e0] = acc;
    __syncthreads();

    if (tid < 2 * E) {
        const int r_idx = tid >> 8, e = tid & 255;
        float v = 0.f;
        #pragma unroll
        for (int c = 0; c < 8; ++c) v += sAc2[c][r_idx][e];
        out[(r0 + r_idx) * E + e] = v;                             // coalesced
    }
}

extern "C" void kernel_launch(void* const* d_in, const int* in_sizes, int n_in,
                              void* d_out, int out_size, void* d_ws, size_t ws_size,
                              hipStream_t stream) {
    // inputs: 0 pos_emb(unused) 1 values 2 ln_w 3 ln_b 4 Wq 5 Wk 6 Wv 7 Wp
    const float* values = (const float*)d_in[1];
    const float* Wv     = (const float*)d_in[6];
    const float* Wp     = (const float*)d_in[7];
    float*       out    = (float*)d_out;
    float*       MT     = (float*)d_ws;  // E*E floats = 256 KB scratch

    build_m_kernel<<<E / 4, 1024, 0, stream>>>(Wv, Wp, MT);
    apply_kernel<<<BT / 2, 1024, 0, stream>>>(values, MT, out);
}